// Round 6
// baseline (279.258 us; speedup 1.0000x reference)
//
#include <hip/hip_runtime.h>
#include <hip/hip_fp16.h>
#include <math.h>

#define CH 128          // IN_CH == OUT_CH == 128
#define NEG_SLOPE 0.2f
#define LN_EPS 1e-5f

typedef _Float16 f16;
typedef _Float16 f16x2 __attribute__((ext_vector_type(2)));
typedef _Float16 f16x8 __attribute__((ext_vector_type(8)));
typedef float    f32x4 __attribute__((ext_vector_type(4)));

__device__ __forceinline__ f16x2 u2h(unsigned u) {
    union { unsigned u; f16x2 h; } v; v.u = u; return v.h;
}

// ---------------------------------------------------------------------------
// K1: Wt[col][k] = f16(col<128 ? Wl[k][col] : Wr[k][col-128]);
//     deg[dst]++ for all edges (deg pre-zeroed by memsetAsync).
// ---------------------------------------------------------------------------
__global__ void k_prep_count(const float* __restrict__ Wl, const float* __restrict__ Wr,
                             f16* __restrict__ Wt,
                             const int* __restrict__ ei, int E, int* __restrict__ deg)
{
    int tid = blockIdx.x * 256 + threadIdx.x;
    if (tid < 256 * CH) {
        int k   = tid >> 8;
        int col = tid & 255;
        float w = (col < CH) ? Wl[k * CH + col] : Wr[k * CH + (col - CH)];
        Wt[(size_t)col * CH + k] = (f16)w;
    }
    if (tid < E) atomicAdd(&deg[ei[E + tid]], 1);
}

// ---------------------------------------------------------------------------
// K2: MFMA f16 GEMM; wave computes 16 nodes x 256 cols (K=128).
// A = W columns (m=channel), B = x rows (n=node) => lane holds 4 consecutive
// channels of one node => packed 8B stores.
// ---------------------------------------------------------------------------
__global__ __launch_bounds__(256) void k_transform(
    const float* __restrict__ x, const f16* __restrict__ Wt,
    const float* __restrict__ bl, const float* __restrict__ br,
    f16* __restrict__ xlh, f16* __restrict__ xrh, int N)
{
    const int wave = (blockIdx.x * 256 + threadIdx.x) >> 6;
    const int lane = threadIdx.x & 63;
    const int m0   = wave * 16;
    if (m0 >= N) return;

    const int n16  = lane & 15;
    const int quad = lane >> 4;

    f16x8 xfr[4];
    {
        int mrow = m0 + n16; if (mrow >= N) mrow = N - 1;
        const float* xrow = x + (size_t)mrow * CH + quad * 8;
#pragma unroll
        for (int ks = 0; ks < 4; ++ks) {
            float4 p0 = *(const float4*)(xrow + ks * 32);
            float4 p1 = *(const float4*)(xrow + ks * 32 + 4);
            f16x8 f; f[0] = (f16)p0.x; f[1] = (f16)p0.y; f[2] = (f16)p0.z; f[3] = (f16)p0.w;
                     f[4] = (f16)p1.x; f[5] = (f16)p1.y; f[6] = (f16)p1.z; f[7] = (f16)p1.w;
            xfr[ks] = f;
        }
    }

#pragma unroll
    for (int ct = 0; ct < 16; ++ct) {
        f32x4 acc = {0.f, 0.f, 0.f, 0.f};
        const int acol = ct * 16 + n16;                       // A row = channel
        const f16* wp = Wt + (size_t)acol * CH + quad * 8;
#pragma unroll
        for (int ks = 0; ks < 4; ++ks) {
            f16x8 afr = *(const f16x8*)(wp + ks * 32);
            acc = __builtin_amdgcn_mfma_f32_16x16x32_f16(afr, xfr[ks], acc, 0, 0, 0);
        }
        const int node = m0 + n16;
        const int chq  = ct * 16 + quad * 4;
        if (node < N) {
            if (ct < 8) {
                float4 bv = *(const float4*)&bl[chq];
                f16x2 p0 = {(f16)(acc[0] + bv.x), (f16)(acc[1] + bv.y)};
                f16x2 p1 = {(f16)(acc[2] + bv.z), (f16)(acc[3] + bv.w)};
                f16* dst = xlh + (size_t)node * CH + chq;
                *(f16x2*)dst = p0; *(f16x2*)(dst + 2) = p1;
            } else {
                int cc = chq - CH;
                float4 bv = *(const float4*)&br[cc];
                f16x2 p0 = {(f16)(acc[0] + bv.x), (f16)(acc[1] + bv.y)};
                f16x2 p1 = {(f16)(acc[2] + bv.z), (f16)(acc[3] + bv.w)};
                f16* dst = xrh + (size_t)node * CH + cc;
                *(f16x2*)dst = p0; *(f16x2*)(dst + 2) = p1;
            }
        }
    }
}

// ---------------------------------------------------------------------------
// K3: segment allocation (replaces global scan). Per-wave shfl scan of
// cnt = deg+1, one atomicAdd on a global counter per wave, cur[i] = seg start.
// Segment order is nondeterministic — softmax sums are order-independent
// up to fp rounding, well under threshold.
// ---------------------------------------------------------------------------
__global__ void k_alloc(const int* __restrict__ deg, int* __restrict__ cur,
                        int* __restrict__ gcount, int N)
{
    int i    = blockIdx.x * 256 + threadIdx.x;
    int lane = threadIdx.x & 63;
    int cnt  = (i < N) ? deg[i] + 1 : 0;      // +1 self-loop
    int incl = cnt;
#pragma unroll
    for (int off = 1; off < 64; off <<= 1) {
        int t = __shfl_up(incl, off);
        if (lane >= off) incl += t;
    }
    int base = 0;
    if (lane == 63) base = atomicAdd(gcount, incl);
    base = __shfl(base, 63);
    if (i < N) cur[i] = base + incl - cnt;    // exclusive start
}

// ---------------------------------------------------------------------------
// K4: scatter-fill CSR. After this, cur[n] = start + cnt = end.
// ---------------------------------------------------------------------------
__global__ void k_fill(const int* __restrict__ ei, int E, int N,
                       int* __restrict__ cur, int* __restrict__ col)
{
    int e = blockIdx.x * 256 + threadIdx.x;
    if (e < E) {
        int s = ei[e];
        int d = ei[E + e];
        int pos = atomicAdd(&cur[d], 1);
        col[pos] = s;
    } else if (e < E + N) {
        int n = e - E;
        int pos = atomicAdd(&cur[n], 1);
        col[pos] = n;
    }
}

// ---------------------------------------------------------------------------
// K5: aggregation + bias + SiLU + LayerNorm. One wave per node.
// lane = g*16+q: g = edge slot (4 edges/wave-iter), q = channel slice
// (8 consecutive channels, head = q>>2). Per 4 edges: ONE dwordx4 gather,
// 16 packed-f16 score ops, 2-step DPP quad reduce, 1 exp, 8 fma_mix.
// Cross-group (x4) acc reduce once per node at the end.
// ---------------------------------------------------------------------------
__global__ __launch_bounds__(256) void k_aggregate(
    const f16* __restrict__ xlh, const f16* __restrict__ xrh,
    const int* __restrict__ col, const int* __restrict__ cur,
    const int* __restrict__ deg,
    const float* __restrict__ att, const float* __restrict__ bias,
    const float* __restrict__ gamma, const float* __restrict__ beta,
    float* __restrict__ out, int N)
{
    const int wid  = threadIdx.x >> 6;
    const int lane = threadIdx.x & 63;
    const int n    = blockIdx.x * 4 + wid;
    if (n >= N) return;

    const int g = lane >> 4;      // edge slot within group-of-4
    const int q = lane & 15;      // channel slice: ch q*8 .. q*8+7

    const int end   = cur[n];
    const int cnt   = deg[n] + 1;
    const int start = end - cnt;

    // per-lane constants: 8 channels of xr and att (f16x2 x4)
    f16x2 xr_s[4], at_s[4];
    {
        uint4 u = *(const uint4*)(xrh + (size_t)n * CH + q * 8);
        xr_s[0] = u2h(u.x); xr_s[1] = u2h(u.y);
        xr_s[2] = u2h(u.z); xr_s[3] = u2h(u.w);
        const float* ap = att + q * 8;
        float4 a0 = *(const float4*)ap;
        float4 a1 = *(const float4*)(ap + 4);
        at_s[0] = (f16x2){(f16)a0.x, (f16)a0.y};
        at_s[1] = (f16x2){(f16)a0.z, (f16)a0.w};
        at_s[2] = (f16x2){(f16)a1.x, (f16)a1.y};
        at_s[3] = (f16x2){(f16)a1.z, (f16)a1.w};
    }
    const f16x2 c02 = {(f16)NEG_SLOPE, (f16)NEG_SLOPE};

    float l_run = 0.f;
    float acc[8] = {0.f, 0.f, 0.f, 0.f, 0.f, 0.f, 0.f, 0.f};

    auto body = [&](uint4 gv, int pe) {
        f16x2 u0 = u2h(gv.x), u1 = u2h(gv.y), u2v = u2h(gv.z), u3 = u2h(gv.w);
        f16x2 t0 = u0 + xr_s[0], t1 = u1 + xr_s[1];
        f16x2 t2 = u2v + xr_s[2], t3 = u3 + xr_s[3];
        t0 = __builtin_elementwise_max(t0, t0 * c02);   // leaky_relu
        t1 = __builtin_elementwise_max(t1, t1 * c02);
        t2 = __builtin_elementwise_max(t2, t2 * c02);
        t3 = __builtin_elementwise_max(t3, t3 * c02);
        float s = __builtin_amdgcn_fdot2(t0, at_s[0], 0.f, false);
        s = __builtin_amdgcn_fdot2(t1, at_s[1], s, false);
        s = __builtin_amdgcn_fdot2(t2, at_s[2], s, false);
        s = __builtin_amdgcn_fdot2(t3, at_s[3], s, false);
        // all-reduce over the 4 lanes of this head (quad_perm DPP)
        int t;
        t = __builtin_amdgcn_update_dpp(0, __builtin_bit_cast(int, s), 0xB1, 0xF, 0xF, false);
        s += __builtin_bit_cast(float, t);
        t = __builtin_amdgcn_update_dpp(0, __builtin_bit_cast(int, s), 0x4E, 0xF, 0xF, false);
        s += __builtin_bit_cast(float, t);
        float w = (pe < end) ? __expf(s) : 0.f;
        l_run += w;
        acc[0] += (float)u0[0] * w;  acc[1] += (float)u0[1] * w;
        acc[2] += (float)u1[0] * w;  acc[3] += (float)u1[1] * w;
        acc[4] += (float)u2v[0] * w; acc[5] += (float)u2v[1] * w;
        acc[6] += (float)u3[0] * w;  acc[7] += (float)u3[1] * w;
    };

    for (int p = start; p < end; p += 8) {
        int pe0 = p + g;
        int pc0 = pe0 < end ? pe0 : end - 1;
        int s0  = col[pc0];
        uint4 gv0 = *(const uint4*)(xlh + (((size_t)(unsigned)s0) << 7) + q * 8);
        if (p + 4 < end) {         // wave-uniform branch
            int pe1 = p + 4 + g;
            int pc1 = pe1 < end ? pe1 : end - 1;
            int s1v = col[pc1];
            uint4 gv1 = *(const uint4*)(xlh + (((size_t)(unsigned)s1v) << 7) + q * 8);
            body(gv0, pe0);
            body(gv1, pe1);
        } else {
            body(gv0, pe0);
        }
    }

    // cross-group reduce (groups hold disjoint edge subsets of the same node)
#pragma unroll
    for (int j = 0; j < 8; ++j) {
        acc[j] += __shfl_xor(acc[j], 16);
        acc[j] += __shfl_xor(acc[j], 32);
    }
    l_run += __shfl_xor(l_run, 16);
    l_run += __shfl_xor(l_run, 32);

    // epilogue: 8 consecutive channels per lane (replicated across groups)
    const int c = q * 8;
    const float inv = 1.f / l_run;
    float4 b0 = *(const float4*)&bias[c];
    float4 b1 = *(const float4*)&bias[c + 4];
    float bb[8] = {b0.x, b0.y, b0.z, b0.w, b1.x, b1.y, b1.z, b1.w};
    float y[8];
    float s1 = 0.f, s2 = 0.f;
#pragma unroll
    for (int j = 0; j < 8; ++j) {
        float v = acc[j] * inv + bb[j];
        v = v / (1.f + __expf(-v));       // SiLU
        y[j] = v;
        s1 += v;
        s2 += v * v;
    }
#pragma unroll
    for (int off = 1; off < 16; off <<= 1) {
        s1 += __shfl_xor(s1, off);
        s2 += __shfl_xor(s2, off);
    }
    float mu   = s1 * (1.f / 128.f);
    float var  = s2 * (1.f / 128.f) - mu * mu;
    float rstd = rsqrtf(var + LN_EPS);
    if (g == 0) {
        float4 g0 = *(const float4*)&gamma[c];
        float4 g1 = *(const float4*)&gamma[c + 4];
        float4 e0 = *(const float4*)&beta[c];
        float4 e1 = *(const float4*)&beta[c + 4];
        float gg[8] = {g0.x, g0.y, g0.z, g0.w, g1.x, g1.y, g1.z, g1.w};
        float ee[8] = {e0.x, e0.y, e0.z, e0.w, e1.x, e1.y, e1.z, e1.w};
        float4 o0, o1;
        float* o0p = (float*)&o0; float* o1p = (float*)&o1;
#pragma unroll
        for (int j = 0; j < 4; ++j) o0p[j] = (y[j] - mu) * rstd * gg[j] + ee[j];
#pragma unroll
        for (int j = 0; j < 4; ++j) o1p[j] = (y[4 + j] - mu) * rstd * gg[4 + j] + ee[4 + j];
        float* dst = out + (size_t)n * CH + c;
        *(float4*)dst = o0;
        *(float4*)(dst + 4) = o1;
    }
}

// ---------------------------------------------------------------------------
extern "C" void kernel_launch(void* const* d_in, const int* in_sizes, int n_in,
                              void* d_out, int out_size, void* d_ws, size_t ws_size,
                              hipStream_t stream)
{
    const float* x    = (const float*)d_in[0];
    const int*   ei   = (const int*)  d_in[1];
    const float* Wl   = (const float*)d_in[2];
    const float* bl   = (const float*)d_in[3];
    const float* Wr   = (const float*)d_in[4];
    const float* br   = (const float*)d_in[5];
    const float* att  = (const float*)d_in[6];
    const float* bias = (const float*)d_in[7];
    const float* gam  = (const float*)d_in[8];
    const float* bet  = (const float*)d_in[9];
    float* out = (float*)d_out;

    const int N  = in_sizes[0] / CH;      // 50000
    const int E  = in_sizes[1] / 2;       // 800000
    const int EN = E + N;

    char* ws = (char*)d_ws;
    size_t off = 0;
    auto carve = [&](size_t bytes) -> char* {
        char* p = ws + off;
        off += (bytes + 255) & ~(size_t)255;
        return p;
    };
    f16* xlh = (f16*)carve((size_t)N * CH * sizeof(f16));
    f16* xrh = (f16*)carve((size_t)N * CH * sizeof(f16));
    f16* Wt  = (f16*)carve((size_t)256 * CH * sizeof(f16));
    int* deg    = (int*)carve(((size_t)N + 1) * sizeof(int));  // +1 = gcount
    int* cur    = (int*)carve((size_t)N * sizeof(int));
    int* colidx = (int*)carve((size_t)EN * sizeof(int));
    int* gcount = deg + N;
    (void)ws_size;

    const int nwaves  = (N + 15) / 16;
    const int tblocks = (nwaves * 64 + 255) / 256;

    hipMemsetAsync(deg, 0, ((size_t)N + 1) * sizeof(int), stream);
    k_prep_count<<<(E + 255) / 256, 256, 0, stream>>>(Wl, Wr, Wt, ei, E, deg);
    k_transform <<<tblocks, 256, 0, stream>>>(x, Wt, bl, br, xlh, xrh, N);
    k_alloc     <<<(N + 255) / 256, 256, 0, stream>>>(deg, cur, gcount, N);
    k_fill      <<<(EN + 255) / 256, 256, 0, stream>>>(ei, E, N, cur, colidx);
    k_aggregate <<<(N + 3) / 4, 256, 0, stream>>>(xlh, xrh, colidx, cur, deg,
                                                  att, bias, gam, bet, out, N);
}

// Round 7
// 267.670 us; speedup vs baseline: 1.0433x; 1.0433x over previous
//
#include <hip/hip_runtime.h>
#include <hip/hip_fp16.h>
#include <math.h>

#define CH 128          // IN_CH == OUT_CH == 128
#define NEG_SLOPE 0.2f
#define LN_EPS 1e-5f

typedef _Float16 f16;
typedef _Float16 f16x2 __attribute__((ext_vector_type(2)));
typedef _Float16 f16x4 __attribute__((ext_vector_type(4)));
typedef _Float16 f16x8 __attribute__((ext_vector_type(8)));
typedef float    f32x4 __attribute__((ext_vector_type(4)));

__device__ __forceinline__ f16x2 u2h(unsigned u) {
    union { unsigned u; f16x2 h; } v; v.u = u; return v.h;
}

// all-reduce sum within each 16-lane row via DPP (no DS pipe)
__device__ __forceinline__ float row16_allreduce(float x) {
    int t;
    t = __builtin_amdgcn_update_dpp(0, __builtin_bit_cast(int, x), 0xB1, 0xF, 0xF, false); // quad_perm(1,0,3,2)
    x += __builtin_bit_cast(float, t);
    t = __builtin_amdgcn_update_dpp(0, __builtin_bit_cast(int, x), 0x4E, 0xF, 0xF, false); // quad_perm(2,3,0,1)
    x += __builtin_bit_cast(float, t);
    t = __builtin_amdgcn_update_dpp(0, __builtin_bit_cast(int, x), 0x141, 0xF, 0xF, false); // row_half_mirror
    x += __builtin_bit_cast(float, t);
    t = __builtin_amdgcn_update_dpp(0, __builtin_bit_cast(int, x), 0x140, 0xF, 0xF, false); // row_mirror
    x += __builtin_bit_cast(float, t);
    return x;
}

// ---------------------------------------------------------------------------
// K1: init — Wt[col][k] = f16(W cat), deg[]=0, gcount=0. One dispatch.
// ---------------------------------------------------------------------------
__global__ void k_init(const float* __restrict__ Wl, const float* __restrict__ Wr,
                       f16* __restrict__ Wt, int* __restrict__ deg,
                       int* __restrict__ gcount, int N)
{
    int tid = blockIdx.x * 256 + threadIdx.x;
    if (tid < 256 * CH) {
        int k   = tid >> 8;
        int col = tid & 255;
        float w = (col < CH) ? Wl[k * CH + col] : Wr[k * CH + (col - CH)];
        Wt[(size_t)col * CH + k] = (f16)w;
    }
    if (tid < N) deg[tid] = 0;
    if (tid == N) *gcount = 0;
}

// ---------------------------------------------------------------------------
// K2: work — blocks [0,TB): MFMA f16 GEMM (16 nodes x 256 cols per wave);
//            blocks [TB,..): deg[dst]++ edge counting. One dispatch, two jobs.
// ---------------------------------------------------------------------------
__global__ __launch_bounds__(256) void k_work(
    const float* __restrict__ x, const f16* __restrict__ Wt,
    const float* __restrict__ bl, const float* __restrict__ br,
    f16* __restrict__ xlh, f16* __restrict__ xrh, int N, int TB,
    const int* __restrict__ ei, int E, int* __restrict__ deg)
{
    if ((int)blockIdx.x >= TB) {
        int e = ((int)blockIdx.x - TB) * 256 + threadIdx.x;
        if (e < E) atomicAdd(&deg[ei[E + e]], 1);
        return;
    }

    const int wave = (blockIdx.x * 256 + threadIdx.x) >> 6;
    const int lane = threadIdx.x & 63;
    const int m0   = wave * 16;
    if (m0 >= N) return;

    const int n16  = lane & 15;
    const int quad = lane >> 4;

    // B-frag: x rows, cvt f32->f16 in-register
    f16x8 xfr[4];
    {
        int mrow = m0 + n16; if (mrow >= N) mrow = N - 1;
        const float* xrow = x + (size_t)mrow * CH + quad * 8;
#pragma unroll
        for (int ks = 0; ks < 4; ++ks) {
            float4 p0 = *(const float4*)(xrow + ks * 32);
            float4 p1 = *(const float4*)(xrow + ks * 32 + 4);
            f16x8 f; f[0] = (f16)p0.x; f[1] = (f16)p0.y; f[2] = (f16)p0.z; f[3] = (f16)p0.w;
                     f[4] = (f16)p1.x; f[5] = (f16)p1.y; f[6] = (f16)p1.z; f[7] = (f16)p1.w;
            xfr[ks] = f;
        }
    }

#pragma unroll
    for (int ct = 0; ct < 16; ++ct) {
        f32x4 acc = {0.f, 0.f, 0.f, 0.f};
        const int acol = ct * 16 + n16;                       // A row = channel
        const f16* wp = Wt + (size_t)acol * CH + quad * 8;
#pragma unroll
        for (int ks = 0; ks < 4; ++ks) {
            f16x8 afr = *(const f16x8*)(wp + ks * 32);
            acc = __builtin_amdgcn_mfma_f32_16x16x32_f16(afr, xfr[ks], acc, 0, 0, 0);
        }
        const int node = m0 + n16;
        const int chq  = ct * 16 + quad * 4;
        if (node < N) {
            if (ct < 8) {
                float4 bv = *(const float4*)&bl[chq];
                f16x4 pk = {(f16)(acc[0] + bv.x), (f16)(acc[1] + bv.y),
                            (f16)(acc[2] + bv.z), (f16)(acc[3] + bv.w)};
                *(f16x4*)(xlh + (size_t)node * CH + chq) = pk;
            } else {
                int cc = chq - CH;
                float4 bv = *(const float4*)&br[cc];
                f16x4 pk = {(f16)(acc[0] + bv.x), (f16)(acc[1] + bv.y),
                            (f16)(acc[2] + bv.z), (f16)(acc[3] + bv.w)};
                *(f16x4*)(xrh + (size_t)node * CH + cc) = pk;
            }
        }
    }
}

// ---------------------------------------------------------------------------
// K3: segment allocation — per-wave shfl scan of cnt=deg+1, one atomicAdd per
// wave. Also zeroes the 16-int tail pad of col.
// ---------------------------------------------------------------------------
__global__ void k_alloc(const int* __restrict__ deg, int* __restrict__ cur,
                        int* __restrict__ gcount, int N, int* __restrict__ colpad)
{
    if (blockIdx.x == 0 && threadIdx.x < 16) colpad[threadIdx.x] = 0;
    int i    = blockIdx.x * 256 + threadIdx.x;
    int lane = threadIdx.x & 63;
    int cnt  = (i < N) ? deg[i] + 1 : 0;      // +1 self-loop
    int incl = cnt;
#pragma unroll
    for (int off = 1; off < 64; off <<= 1) {
        int t = __shfl_up(incl, off);
        if (lane >= off) incl += t;
    }
    int base = 0;
    if (lane == 63) base = atomicAdd(gcount, incl);
    base = __shfl(base, 63);
    if (i < N) cur[i] = base + incl - cnt;    // exclusive start
}

// ---------------------------------------------------------------------------
// K4: scatter-fill CSR. After this, cur[n] = end.
// ---------------------------------------------------------------------------
__global__ void k_fill(const int* __restrict__ ei, int E, int N,
                       int* __restrict__ cur, int* __restrict__ col)
{
    int e = blockIdx.x * 256 + threadIdx.x;
    if (e < E) {
        int s = ei[e];
        int d = ei[E + e];
        int pos = atomicAdd(&cur[d], 1);
        col[pos] = s;
    } else if (e < E + N) {
        int n = e - E;
        int pos = atomicAdd(&cur[n], 1);
        col[pos] = n;
    }
}

// ---------------------------------------------------------------------------
// K5: aggregation + bias + SiLU + LayerNorm. One wave per node.
// lane owns channel pair (2l, 2l+1); head = lane>>4. Per edge: one dword
// gather (256B/row across wave), packed-f16 score, 4-step DPP head-reduce,
// exp, fma_mix accumulate. Unroll 8 + software-pipelined col prefetch:
// 8 gathers + 8 next-col loads in flight per iteration (MLP ~16).
// ---------------------------------------------------------------------------
__global__ __launch_bounds__(256) void k_aggregate(
    const f16* __restrict__ xlh, const f16* __restrict__ xrh,
    const int* __restrict__ col, const int* __restrict__ cur,
    const int* __restrict__ deg,
    const float* __restrict__ att, const float* __restrict__ bias,
    const float* __restrict__ gamma, const float* __restrict__ beta,
    float* __restrict__ out, int N)
{
    const int wid  = threadIdx.x >> 6;
    const int lane = threadIdx.x & 63;
    const int n    = blockIdx.x * 4 + wid;
    if (n >= N) return;

    const int end   = cur[n];
    const int cnt   = deg[n] + 1;
    const int start = end - cnt;

    const int c = 2 * lane;
    f16x2 xr2, at2;
    {
        xr2 = *(const f16x2*)&xrh[(size_t)n * CH + c];
        float2 a = *(const float2*)&att[c];
        at2 = (f16x2){(f16)a.x, (f16)a.y};
    }
    const f16x2 c02 = {(f16)NEG_SLOPE, (f16)NEG_SLOPE};
    const unsigned laneoff = (unsigned)c;     // halfword offset within row

    float l_run = 0.f;
    float accx = 0.f, accy = 0.f;

    // software pipeline: col indices for the current 8-edge block
    int cc[8];
#pragma unroll
    for (int k = 0; k < 8; ++k) cc[k] = col[start + k];   // pad makes this safe

    for (int p = start; p < end; p += 8) {
        // issue all 8 gathers (addresses ready)
        unsigned gv[8];
#pragma unroll
        for (int k = 0; k < 8; ++k)
            gv[k] = *(const unsigned*)(xlh + (((size_t)(unsigned)cc[k]) << 7) + laneoff);
        // prefetch next block's col indices (pad: col has 16 zeroed tail ints)
#pragma unroll
        for (int k = 0; k < 8; ++k) cc[k] = col[p + 8 + k];
        // compute 8 edges
#pragma unroll
        for (int k = 0; k < 8; ++k) {
            f16x2 u  = u2h(gv[k]);
            f16x2 tt = u + xr2;                                   // v_pk_add_f16
            f16x2 lk = __builtin_elementwise_max(tt, tt * c02);   // leaky_relu
            float s  = __builtin_amdgcn_fdot2(lk, at2, 0.f, false);
            s = row16_allreduce(s);
            float w = (p + k < end) ? __expf(s) : 0.f;
            l_run += w;
            accx += (float)u[0] * w;                              // v_fma_mix
            accy += (float)u[1] * w;
        }
    }

    const float inv = 1.f / l_run;    // l_run identical within head group
    float y0 = accx * inv + bias[c];
    float y1 = accy * inv + bias[c + 1];
    y0 = y0 / (1.f + __expf(-y0));    // SiLU
    y1 = y1 / (1.f + __expf(-y1));
    float s1 = y0 + y1;
    float s2 = y0 * y0 + y1 * y1;
#pragma unroll
    for (int off = 1; off < 64; off <<= 1) {
        s1 += __shfl_xor(s1, off);
        s2 += __shfl_xor(s2, off);
    }
    float mu   = s1 * (1.f / 128.f);
    float var  = s2 * (1.f / 128.f) - mu * mu;
    float rstd = rsqrtf(var + LN_EPS);
    float o0 = (y0 - mu) * rstd * gamma[c]     + beta[c];
    float o1 = (y1 - mu) * rstd * gamma[c + 1] + beta[c + 1];
    *(float2*)&out[(size_t)n * CH + c] = make_float2(o0, o1);
}

// ---------------------------------------------------------------------------
extern "C" void kernel_launch(void* const* d_in, const int* in_sizes, int n_in,
                              void* d_out, int out_size, void* d_ws, size_t ws_size,
                              hipStream_t stream)
{
    const float* x    = (const float*)d_in[0];
    const int*   ei   = (const int*)  d_in[1];
    const float* Wl   = (const float*)d_in[2];
    const float* bl   = (const float*)d_in[3];
    const float* Wr   = (const float*)d_in[4];
    const float* br   = (const float*)d_in[5];
    const float* att  = (const float*)d_in[6];
    const float* bias = (const float*)d_in[7];
    const float* gam  = (const float*)d_in[8];
    const float* bet  = (const float*)d_in[9];
    float* out = (float*)d_out;

    const int N  = in_sizes[0] / CH;      // 50000
    const int E  = in_sizes[1] / 2;       // 800000
    const int EN = E + N;

    char* ws = (char*)d_ws;
    size_t off = 0;
    auto carve = [&](size_t bytes) -> char* {
        char* p = ws + off;
        off += (bytes + 255) & ~(size_t)255;
        return p;
    };
    f16* xlh = (f16*)carve((size_t)N * CH * sizeof(f16));
    f16* xrh = (f16*)carve((size_t)N * CH * sizeof(f16));
    f16* Wt  = (f16*)carve((size_t)256 * CH * sizeof(f16));
    int* deg    = (int*)carve(((size_t)N + 1) * sizeof(int));  // +1 = gcount
    int* cur    = (int*)carve((size_t)N * sizeof(int));
    int* colidx = (int*)carve(((size_t)EN + 16) * sizeof(int)); // +16 zero pad
    int* gcount = deg + N;
    (void)ws_size;

    const int nwaves = (N + 15) / 16;                   // GEMM waves
    const int TB     = (nwaves * 64 + 255) / 256;       // transform blocks
    const int CB     = (E + 255) / 256;                 // count blocks
    const int IB     = (N + 256) / 256 + 1;             // init covers N+1 ids

    k_init      <<<IB, 256, 0, stream>>>(Wl, Wr, Wt, deg, gcount, N);
    k_work      <<<TB + CB, 256, 0, stream>>>(x, Wt, bl, br, xlh, xrh, N, TB, ei, E, deg);
    k_alloc     <<<(N + 255) / 256, 256, 0, stream>>>(deg, cur, gcount, N, colidx + EN);
    k_fill      <<<(EN + 255) / 256, 256, 0, stream>>>(ei, E, N, cur, colidx);
    k_aggregate <<<(N + 3) / 4, 256, 0, stream>>>(xlh, xrh, colidx, cur, deg,
                                                  att, bias, gam, bet, out, N);
}